// Round 5
// baseline (457.817 us; speedup 1.0000x reference)
//
#include <hip/hip_runtime.h>
#include <math.h>

#define HIDDEN   4096
#define NEXP     64
#define NTOK     16384
#define KCHUNKS  8
#define KC       (HIDDEN / KCHUNKS)   // 512 k per chunk
#define BK       16                   // k per LDS stage
#define ITERS    (KC / BK)            // 32
#define BT       64                   // tokens per block

// ---------------- Kernel 1: split-K fp32 GEMM -> partial logits ----------------
// grid (256 token tiles, 8 k-chunks), block = 128 threads (2 waves = 2 expert halves).
// 4096 waves total -> 4 waves/SIMD (round-4 was 2/SIMD and latency-exposed).
// Both waves share one X tile + one W tile (x fetched exactly once from HBM).
// Staging: wave 0 stages X, wave 1 stages W via global_load_lds_dwordx4 (linear
// dest per wave), XOR-swizzled rows: element (row r, k=4G+dk) at word
//   r*16 + 4*(G ^ ((r>>3)&3)) + dk          (same verified swizzle as round 4)
// Reads (all 2-way-or-broadcast, conflict-free):
//   xq (i=lane>>3 varies): 4 bank-quads x 2-way x 8-lane broadcast
//   WV (j=lane&7 varies):  4 bank-quads x 2-way x 8-lane broadcast
// Per-lane 8x4 tile: per 4-k group, 12 ds_read_b128 -> 128 FMA.
// fmaf chain per (token,expert): k ascending 0..511 within chunk — bit-identical
// to rounds 0-4 (passed, absmax 0.0).
__global__ __launch_bounds__(128, 4)
void gemm_partial(const float* __restrict__ x, const float* __restrict__ W,
                  float* __restrict__ part) {
    __shared__ float lds[2][2][64 * BK];   // [buf][X=0/W=1][64 rows x 16 words] = 16 KB

    const int tid  = threadIdx.x;
    const int lane = tid & 63;
    const int eh   = tid >> 6;         // wave id = expert half (0/1), wave-uniform
    const int t0   = blockIdx.x * BT;
    const int kbase = blockIdx.y * KC;
    const int i = lane >> 3;           // token group (8 tokens)
    const int j = lane & 7;            // expert group (4 experts)

    // staging lane offsets (dwords): instr p covers rows p*16 + (lane>>2);
    // source k-offset = 4*((lane&3) ^ ((2p + (lane>>5)) & 3)) — only p parity matters
    const int srow = lane >> 2;                                   // 0..15
    const int sevn = 4 * ((lane & 3) ^ ((lane >> 5) & 3));        // p = 0, 2
    const int sodd = 4 * ((lane & 3) ^ ((2 + (lane >> 5)) & 3));  // p = 1, 3
    // wave 0 stages X rows (tokens t0+r), wave 1 stages W rows (experts r)
    const float* sbase = (eh == 0) ? (x + (size_t)t0 * HIDDEN) : W;

#define STAGE(buf, itn) do {                                                          \
    _Pragma("unroll")                                                                 \
    for (int p = 0; p < 4; ++p) {                                                     \
        const int ko = kbase + (itn) * BK + ((p & 1) ? sodd : sevn);                  \
        __builtin_amdgcn_global_load_lds(                                             \
            (const __attribute__((address_space(1))) uint32_t*)                       \
                (sbase + (size_t)(p * 16 + srow) * HIDDEN + ko),                      \
            (__attribute__((address_space(3))) uint32_t*)&lds[buf][eh][p * 256],      \
            16, 0, 0);                                                                \
    }                                                                                 \
} while (0)

    float acc[8][4];
#pragma unroll
    for (int m = 0; m < 8; ++m)
#pragma unroll
        for (int e = 0; e < 4; ++e) acc[m][e] = 0.f;

    STAGE(0, 0);
    __syncthreads();   // staging of buf0 visible to both waves

    for (int it = 0; it < ITERS; ++it) {
        const int cb = it & 1;
        if (it + 1 < ITERS) STAGE(cb ^ 1, it + 1);   // loads fly during compute

#pragma unroll
        for (int g = 0; g < 4; ++g) {                // k = it*16 + g*4 + dk, ascending
            float4 WV[4];
#pragma unroll
            for (int e = 0; e < 4; ++e) {
                const int rw = eh * 32 + j * 4 + e;  // expert row
                WV[e] = *(const float4*)&lds[cb][1][rw * BK + 4 * (g ^ ((rw >> 3) & 3))];
            }
#pragma unroll
            for (int m = 0; m < 8; ++m) {
                const int rx = i * 8 + m;            // token row; (rx>>3)&3 == i&3
                const float4 xq = *(const float4*)&lds[cb][0][rx * BK + 4 * (g ^ ((rx >> 3) & 3))];
#pragma unroll
                for (int e = 0; e < 4; ++e) {
                    float a = fmaf(xq.x, WV[e].x, acc[m][e]);
                    a       = fmaf(xq.y, WV[e].y, a);
                    a       = fmaf(xq.z, WV[e].z, a);
                    acc[m][e] = fmaf(xq.w, WV[e].w, a);
                }
            }
        }
        __syncthreads();   // cb reads done in both waves before it+1 overwrites; drains prefetch
    }
#undef STAGE

    // write partial logits: part[kc][token][eh*32 + j*4 .. +3]
    float* dst = part + ((size_t)blockIdx.y * NTOK + t0) * NEXP + eh * 32;
#pragma unroll
    for (int m = 0; m < 8; ++m) {
        const int tok = i * 8 + m;
        *(float4*)&dst[(size_t)tok * NEXP + j * 4] =
            make_float4(acc[m][0], acc[m][1], acc[m][2], acc[m][3]);
    }
}

// ---------------- Kernel 2: reduce partials + bias, softmax, top-2 ----------------
// Byte-identical to the round-0 version (passed, absmax 0.0).
__global__ __launch_bounds__(256)
void softmax_top2(const float* __restrict__ part, const float* __restrict__ bias,
                  float* __restrict__ out) {
    const int lane = threadIdx.x & 63;
    const int wid  = threadIdx.x >> 6;
    const int t    = blockIdx.x * 4 + wid;

    float l = bias[lane];
#pragma unroll
    for (int c = 0; c < KCHUNKS; ++c)
        l += part[((size_t)c * NTOK + t) * NEXP + lane];

    // wave max
    float m = l;
#pragma unroll
    for (int s = 32; s > 0; s >>= 1)
        m = fmaxf(m, __shfl_xor(m, s, 64));

    // softmax denominator (deterministic butterfly)
    float ssum = expf(l - m);
#pragma unroll
    for (int s = 32; s > 0; s >>= 1)
        ssum += __shfl_xor(ssum, s, 64);

    // top-1: max value, lower index wins ties
    float v1 = l; int i1 = lane;
#pragma unroll
    for (int s = 32; s > 0; s >>= 1) {
        float ov = __shfl_xor(v1, s, 64);
        int   oi = __shfl_xor(i1, s, 64);
        if (ov > v1 || (ov == v1 && oi < i1)) { v1 = ov; i1 = oi; }
    }
    // top-2: exclude i1
    float v2 = (lane == i1) ? -INFINITY : l;
    int   i2 = lane;
#pragma unroll
    for (int s = 32; s > 0; s >>= 1) {
        float ov = __shfl_xor(v2, s, 64);
        int   oi = __shfl_xor(i2, s, 64);
        if (ov > v2 || (ov == v2 && oi < i2)) { v2 = ov; i2 = oi; }
    }

    if (lane == 0) {
        const float inv = 1.0f / ssum;
        out[(size_t)t * 2 + 0] = inv;                    // exp(v1-m)=1 since v1==m
        out[(size_t)t * 2 + 1] = expf(v2 - m) * inv;
        out[(size_t)2 * NTOK + t * 2 + 0] = (float)i1;   // indices read back as float32
        out[(size_t)2 * NTOK + t * 2 + 1] = (float)i2;
    }
}

extern "C" void kernel_launch(void* const* d_in, const int* in_sizes, int n_in,
                              void* d_out, int out_size, void* d_ws, size_t ws_size,
                              hipStream_t stream) {
    const float* x  = (const float*)d_in[0];
    const float* W  = (const float*)d_in[1];
    const float* b  = (const float*)d_in[2];
    float* out  = (float*)d_out;
    float* part = (float*)d_ws;   // KCHUNKS*NTOK*NEXP*4 = 32 MB scratch

    dim3 g1(NTOK / BT, KCHUNKS);  // 2048 blocks x 2 waves = 4096 waves (4/SIMD)
    gemm_partial<<<g1, 128, 0, stream>>>(x, W, part);
    softmax_top2<<<NTOK / 4, 256, 0, stream>>>(part, b, out);
}

// Round 7
// 428.147 us; speedup vs baseline: 1.0693x; 1.0693x over previous
//
#include <hip/hip_runtime.h>
#include <math.h>

#define HIDDEN   4096
#define NEXP     64
#define NTOK     16384
#define KCHUNKS  8
#define KC       (HIDDEN / KCHUNKS)   // 512 k per chunk
#define BK       32                   // k per LDS stage
#define ITERS    (KC / BK)            // 16
#define BT       64                   // tokens per block

// ---------- Kernel 0: transpose W (1 MB) into workspace: Wt[k][e] = W[e][k] ----------
__global__ void wtrans(const float* __restrict__ W, float* __restrict__ Wt) {
    const int k  = blockIdx.x * 64 + (threadIdx.x & 63);
    const int e0 = threadIdx.x >> 6;                       // 0..3
#pragma unroll
    for (int ee = 0; ee < 64; ee += 4)                     // coalesced reads along k
        Wt[(size_t)k * NEXP + (ee + e0)] = W[(size_t)(ee + e0) * HIDDEN + k];
}

// ---------------- Kernel 1: split-K fp32 GEMM -> partial logits ----------------
// grid (256 token tiles, 8 k-chunks), block = 256 threads (4 waves = 4 expert groups).
// 8192 waves -> 8/SIMD, 32 waves/CU (max occupancy).
// lane = token. Wave covers 16 experts; W comes from the SCALAR pipe (s_load of
// Wt[k][ebase..ebase+15], all-uniform address), so per k the VALU stream is
// 16 x v_fmac_f32 v,s,v with NO vector-memory traffic interleaved.
// LDS serves only x: 1 ds_read_b128 per 4 k per lane (~20 us/CU total vs the
// 54.6 us/SIMD VALU floor) — rounds 4/5 were LDS-pipe-bound at 82-123 us/CU.
// X tile [64 tok][32 k], XOR-swizzled: element (row r, k=4G+dk) at word
//   r*32 + 4*(G ^ (r&7)) + dk
//   staging (global_load_lds, linear dest): instr p covers row wid*16+p*8+(lane>>3),
//     slot lane&7 -> source k-offset 4*((lane&7) ^ ((lane>>3)&7)), 64B-coalesced
//   reads: quad = g ^ (lane&7) -> each 8-lane group covers all 8 bank-quads = clean
// fmaf chain per (token,expert): k ascending 0..511 within chunk — bit-identical
// to rounds 0-5 (passed, absmax 0.0).
__global__ __launch_bounds__(256, 8)
void gemm_partial(const float* __restrict__ x, const float* __restrict__ Wt,
                  float* __restrict__ part) {
    __shared__ float lds[2][64 * BK];   // double-buffered X tile, 16 KB

    const int tid   = threadIdx.x;
    const int lane  = tid & 63;
    const int wid   = __builtin_amdgcn_readfirstlane(tid >> 6);  // uniform wave id
    const int ebase = wid * 16;                                  // expert group base
    const int t0    = blockIdx.x * BT;
    const int kbase = blockIdx.y * KC;

    const int srow = lane >> 3;                         // + p*8 (staging row within wave)
    const int sko  = 4 * ((lane & 7) ^ ((lane >> 3) & 7));  // pre-swizzled source k-offset

#define STAGE(buf, itn) do {                                                          \
    _Pragma("unroll")                                                                 \
    for (int p = 0; p < 2; ++p) {                                                     \
        __builtin_amdgcn_global_load_lds(                                             \
            (const __attribute__((address_space(1))) uint32_t*)                       \
                (x + (size_t)(t0 + wid * 16 + p * 8 + srow) * HIDDEN                  \
                   + kbase + (itn) * BK + sko),                                       \
            (__attribute__((address_space(3))) uint32_t*)                             \
                &lds[buf][wid * 512 + p * 256],                                       \
            16, 0, 0);                                                                \
    }                                                                                 \
} while (0)

    float acc[16];
#pragma unroll
    for (int e = 0; e < 16; ++e) acc[e] = 0.f;

    STAGE(0, 0);
    __syncthreads();

    for (int it = 0; it < ITERS; ++it) {
        const int cb = it & 1;
        if (it + 1 < ITERS) STAGE(cb ^ 1, it + 1);   // prefetch flies over this tile's FMAs
        const int k0 = kbase + it * BK;

#pragma unroll
        for (int g = 0; g < 8; ++g) {                // k = it*32 + g*4 + dk, ascending
            const float4 xq = *(const float4*)&lds[cb][lane * 32 + 4 * (g ^ (lane & 7))];
#pragma unroll
            for (int dk = 0; dk < 4; ++dk) {
                const float xs = (dk == 0) ? xq.x : (dk == 1) ? xq.y
                               : (dk == 2) ? xq.z : xq.w;
                const float* __restrict__ wrow =
                    Wt + (size_t)(k0 + g * 4 + dk) * NEXP + ebase;  // fully uniform -> s_load
#pragma unroll
                for (int e = 0; e < 16; ++e)
                    acc[e] = fmaf(xs, wrow[e], acc[e]);
            }
        }
        __syncthreads();   // all waves done reading cb; next STAGE may overwrite it
    }
#undef STAGE

    // write partial logits: part[kc][t0+lane][ebase .. ebase+15]
    float* dst = part + ((size_t)blockIdx.y * NTOK + t0 + lane) * NEXP + ebase;
#pragma unroll
    for (int h = 0; h < 4; ++h)
        *(float4*)&dst[h * 4] =
            make_float4(acc[h * 4 + 0], acc[h * 4 + 1], acc[h * 4 + 2], acc[h * 4 + 3]);
}

// ---------------- Kernel 2: reduce partials + bias, softmax, top-2 ----------------
// Byte-identical to the round-0 version (passed, absmax 0.0).
__global__ __launch_bounds__(256)
void softmax_top2(const float* __restrict__ part, const float* __restrict__ bias,
                  float* __restrict__ out) {
    const int lane = threadIdx.x & 63;
    const int wid  = threadIdx.x >> 6;
    const int t    = blockIdx.x * 4 + wid;

    float l = bias[lane];
#pragma unroll
    for (int c = 0; c < KCHUNKS; ++c)
        l += part[((size_t)c * NTOK + t) * NEXP + lane];

    // wave max
    float m = l;
#pragma unroll
    for (int s = 32; s > 0; s >>= 1)
        m = fmaxf(m, __shfl_xor(m, s, 64));

    // softmax denominator (deterministic butterfly)
    float ssum = expf(l - m);
#pragma unroll
    for (int s = 32; s > 0; s >>= 1)
        ssum += __shfl_xor(ssum, s, 64);

    // top-1: max value, lower index wins ties
    float v1 = l; int i1 = lane;
#pragma unroll
    for (int s = 32; s > 0; s >>= 1) {
        float ov = __shfl_xor(v1, s, 64);
        int   oi = __shfl_xor(i1, s, 64);
        if (ov > v1 || (ov == v1 && oi < i1)) { v1 = ov; i1 = oi; }
    }
    // top-2: exclude i1
    float v2 = (lane == i1) ? -INFINITY : l;
    int   i2 = lane;
#pragma unroll
    for (int s = 32; s > 0; s >>= 1) {
        float ov = __shfl_xor(v2, s, 64);
        int   oi = __shfl_xor(i2, s, 64);
        if (ov > v2 || (ov == v2 && oi < i2)) { v2 = ov; i2 = oi; }
    }

    if (lane == 0) {
        const float inv = 1.0f / ssum;
        out[(size_t)t * 2 + 0] = inv;                    // exp(v1-m)=1 since v1==m
        out[(size_t)t * 2 + 1] = expf(v2 - m) * inv;
        out[(size_t)2 * NTOK + t * 2 + 0] = (float)i1;   // indices read back as float32
        out[(size_t)2 * NTOK + t * 2 + 1] = (float)i2;
    }
}

extern "C" void kernel_launch(void* const* d_in, const int* in_sizes, int n_in,
                              void* d_out, int out_size, void* d_ws, size_t ws_size,
                              hipStream_t stream) {
    const float* x  = (const float*)d_in[0];
    const float* W  = (const float*)d_in[1];
    const float* b  = (const float*)d_in[2];
    float* out  = (float*)d_out;
    float* part = (float*)d_ws;                                  // 32 MB partials
    float* Wt   = part + (size_t)KCHUNKS * NTOK * NEXP;          // +1 MB transposed W

    wtrans<<<dim3(HIDDEN / 64), 256, 0, stream>>>(W, Wt);
    dim3 g1(NTOK / BT, KCHUNKS);  // 2048 blocks x 4 waves = 8192 waves (8/SIMD)
    gemm_partial<<<g1, 256, 0, stream>>>(x, Wt, part);
    softmax_top2<<<NTOK / 4, 256, 0, stream>>>(part, b, out);
}